// Round 15
// baseline (104.051 us; speedup 1.0000x reference)
//
#include <hip/hip_runtime.h>
#include <hip/hip_bf16.h>
#include <cstdint>
#include <cstddef>

#define TOKENS 8192
#define IN_F   1024
#define OUT_F  1024
#define ROWB   7168          // row stride bytes: 5120 i8 (P1..P5) + 2048 bf16 (silu)
#define B0     0
#define B1     16384
#define B2     32768

typedef __attribute__((ext_vector_type(4))) float          f32x4;
typedef __attribute__((ext_vector_type(4))) float          float4v;
typedef __attribute__((ext_vector_type(4))) int            i32x4;
typedef __attribute__((ext_vector_type(8))) __bf16         bf16x8;
typedef __attribute__((ext_vector_type(8))) unsigned short ushort8;
typedef __attribute__((ext_vector_type(8))) char           char8;

__device__ __forceinline__ unsigned short f2bf(float f) {
    unsigned int u = __builtin_bit_cast(unsigned int, f);
    u += 0x7FFFu + ((u >> 16) & 1u);
    return (unsigned short)(u >> 16);
}

// ============================================================================
// Kernel 1 (merged): blocks 0..4095 = activations; 4096..5119 = weights.
//   act: Arow[b][0..5119]=P1..P5 i8 (x63.5), [5120..7167]=silu bf16.
//   wt:  Brow[o] same layout from C/W; scaleC[o]; bias+C0-fold -> bias_aug.
// ============================================================================
__global__ __launch_bounds__(256) void prep_kernel(const float* __restrict__ x,
                                                   const float* __restrict__ W,
                                                   const float* __restrict__ C,
                                                   const float* __restrict__ bias,
                                                   char* __restrict__ Arow,
                                                   char* __restrict__ Brow,
                                                   float* __restrict__ scaleC,
                                                   float* __restrict__ bias_aug) {
    __shared__ float redS[4], redM[4];
    int tid = threadIdx.x;
    if (blockIdx.x < 4096) {
        // ---------------- activation part ----------------
        int gid = blockIdx.x * 256 + tid;
        int b   = gid >> 7;
        int i8  = (gid & 127) << 3;

        const float* xp = x + (size_t)b * IN_F + i8;
        float xs[8];
        *(float4v*)&xs[0] = *(const float4v*)xp;
        *(float4v*)&xs[4] = *(const float4v*)(xp + 4);

        unsigned short sres[8];
        char8 q[5];
        #pragma unroll
        for (int e = 0; e < 8; ++e) {
            float v  = xs[e];
            float s  = v / (1.f + __expf(-v));
            float t  = 1.f - 2.f / (1.f + __expf(2.f * v));
            float p1 = 2.f * t;
            float p2 = (12.f / 24.f) * t * p1 - (8.f / 24.f) * 1.f;
            float p3 = (64.f / 120.f) * t * p2 - (48.f / 120.f) * p1;
            float p4 = (180.f / 336.f) * t * p3 - (144.f / 336.f) * p2;
            float p5 = (384.f / 720.f) * t * p4 - (320.f / 720.f) * p3;
            sres[e] = f2bf(s);
            q[0][e] = (char)__float2int_rn(p1 * 63.5f);
            q[1][e] = (char)__float2int_rn(p2 * 63.5f);
            q[2][e] = (char)__float2int_rn(p3 * 63.5f);
            q[3][e] = (char)__float2int_rn(p4 * 63.5f);
            q[4][e] = (char)__float2int_rn(p5 * 63.5f);
        }
        char* row = Arow + (size_t)b * ROWB;
        #pragma unroll
        for (int k = 0; k < 5; ++k)
            *(char8*)(row + k * 1024 + i8) = q[k];
        *(ushort8*)(row + 5120 + i8 * 2) = *(const ushort8*)&sres[0];
    } else {
        // ---------------- weight part ----------------
        int o = blockIdx.x - 4096;
        char* row = Brow + (size_t)o * ROWB;
        float cv[4][5];
        float biasacc = 0.f, amax = 0.f;
        #pragma unroll
        for (int j = 0; j < 4; ++j) {
            int i = tid + j * 256;
            *(unsigned short*)(row + 5120 + i * 2) = f2bf(W[(size_t)o * IN_F + i]);
            const float* c = C + ((size_t)o * IN_F + i) * 6;
            biasacc += c[0];
            #pragma unroll
            for (int k = 0; k < 5; ++k) {
                float v = c[k + 1];
                cv[j][k] = v;
                amax = fmaxf(amax, fabsf(v));
            }
        }
        #pragma unroll
        for (int off = 32; off > 0; off >>= 1) {
            biasacc += __shfl_down(biasacc, off, 64);
            amax = fmaxf(amax, __shfl_down(amax, off, 64));
        }
        int lane = tid & 63, wv = tid >> 6;
        if (lane == 0) { redS[wv] = biasacc; redM[wv] = amax; }
        __syncthreads();
        float rA = fmaxf(fmaxf(redM[0], redM[1]), fmaxf(redM[2], redM[3]));
        rA = fmaxf(rA, 1e-20f);
        float rinv = 127.f / rA;
        if (tid == 0) {
            scaleC[o]   = rA / 127.f;
            bias_aug[o] = bias[o] + redS[0] + redS[1] + redS[2] + redS[3];
        }
        #pragma unroll
        for (int j = 0; j < 4; ++j) {
            int i = tid + j * 256;
            #pragma unroll
            for (int k = 0; k < 5; ++k)
                row[k * 1024 + i] = (char)__float2int_rn(cv[j][k] * rinv);
        }
    }
}

// ============================================================================
// Kernel 2: fused GEMM, 128x128 tile, 512 thr = 8 waves (2M x 4N, wave-tile
//   64x32), grid 512 = 2 blocks/CU = 16 waves/CU = 4 waves/SIMD.
//   launch_bounds(512,4): VGPR cap 128 (required for 16-wave residency).
//   LDS 48KB = 3 bufs x [A 128x64B | B 128x64B], zero-conflict XOR swizzle.
//   Per tile T (same-phase reads, m201-style role-split cover):
//     STAGE(T+2) (2 gloads) | vmcnt(4) [retires stage(T)] | BAR |
//     RD(T) 6 reads | lgkm(0) | 8 MFMA | BAR
//   WAR: stage(T+2)->buf (T-1)%3; its readers drained at lgkm(0)@T-1 before
//   end-BAR@T-1; stage@T follows that barrier -> safe with 3 bufs.
//   Tiles 0..79 i8 (mfma_i32_16x16x64_i8), 80..111 bf16; separate accI/accF.
// ============================================================================
__global__ __launch_bounds__(512, 4) void gemm_kernel(
    const char* __restrict__ Arow,
    const char* __restrict__ Brow,
    const float* __restrict__ scaleC,
    const float* __restrict__ bias_aug,
    float* __restrict__ out)
{
    __shared__ __align__(16) char ldsc[49152];   // 3 x 16KB

    const int tid  = threadIdx.x;
    const int lane = tid & 63;
    const int wave = tid >> 6;              // 0..7
    const int wr   = wave >> 2;             // 0..1 (M)
    const int wc   = wave & 3;              // 0..3 (N)
    const int fr   = lane & 15;
    const int fg   = lane >> 4;
    const int wrbase = wr * 64;
    const int wcbase = wc * 32;

    // XCD-local decode: bm-sharing blocks stay on one XCD (A fetched once).
    const int bm = (blockIdx.x & 7) * 8 + ((blockIdx.x >> 3) & 7);  // 0..63
    const int bn = blockIdx.x >> 6;                                  // 0..7

    // staging: dest linear tid*16 (512 thr x 16B = 8KB = 128 rows x 64B);
    // dest row r0 = tid>>2, slot tid&3; source slot = (tid&3)^((r0>>1)&3).
    const int r0   = tid >> 2;
    const int sswz = ((tid & 3) ^ ((tid >> 3) & 3)) << 4;
    const char* gA = Arow + (size_t)(bm * 128 + r0) * ROWB + sswz;
    const char* gB = Brow + (size_t)(bn * 128 + r0) * ROWB + sswz;

    // ds_read swizzled slot within 64B row ((row>>1)&3 == (fr>>1)&3)
    const int kcs = (fg << 4) ^ (((fr >> 1) & 3) << 4);

    i32x4 accI[4][2] = {};
    f32x4 accF[4][2];
    i32x4 af[4], bf_[2];

    float sc_[2];
    #pragma unroll
    for (int ni = 0; ni < 2; ++ni)
        sc_[ni] = scaleC[bn * 128 + wcbase + ni * 16 + fr] * (1.f / 63.5f);

#define GLDS(SRC, DST) __builtin_amdgcn_global_load_lds(                        \
    (const __attribute__((address_space(1))) void*)(SRC),                       \
    (__attribute__((address_space(3))) void*)(DST), 16, 0, 0)

#define STAGE(S, BO) do {                                                       \
    const size_t _ko = (size_t)(S) * 64;                                        \
    GLDS(gA + _ko, ldsc + (BO) + tid * 16);                                     \
    GLDS(gB + _ko, ldsc + (BO) + 8192 + tid * 16);                              \
} while (0)

#define RD(BO) do {                                                             \
    _Pragma("unroll")                                                           \
    for (int i_ = 0; i_ < 4; ++i_)                                              \
        af[i_] = *(const i32x4*)(ldsc + (BO) + (wrbase + i_ * 16 + fr) * 64 + kcs); \
    _Pragma("unroll")                                                           \
    for (int i_ = 0; i_ < 2; ++i_)                                              \
        bf_[i_] = *(const i32x4*)(ldsc + (BO) + 8192 + (wcbase + i_ * 16 + fr) * 64 + kcs); \
} while (0)

#define MFI() do { __builtin_amdgcn_s_setprio(1);                               \
    _Pragma("unroll")                                                           \
    for (int mi_ = 0; mi_ < 4; ++mi_)                                           \
        _Pragma("unroll")                                                       \
        for (int ni_ = 0; ni_ < 2; ++ni_)                                       \
            accI[mi_][ni_] = __builtin_amdgcn_mfma_i32_16x16x64_i8(             \
                af[mi_], bf_[ni_], accI[mi_][ni_], 0, 0, 0);                    \
    __builtin_amdgcn_s_setprio(0); } while (0)

#define MFF() do { __builtin_amdgcn_s_setprio(1);                               \
    _Pragma("unroll")                                                           \
    for (int mi_ = 0; mi_ < 4; ++mi_)                                           \
        _Pragma("unroll")                                                       \
        for (int ni_ = 0; ni_ < 2; ++ni_)                                       \
            accF[mi_][ni_] = __builtin_amdgcn_mfma_f32_16x16x32_bf16(           \
                __builtin_bit_cast(bf16x8, af[mi_]),                            \
                __builtin_bit_cast(bf16x8, bf_[ni_]),                           \
                accF[mi_][ni_], 0, 0, 0);                                       \
    __builtin_amdgcn_s_setprio(0); } while (0)

#define TILE(T, MF, RDB, STB, DOST, CNT) do {                                   \
    if (DOST) STAGE((T) + 2, (STB));                                            \
    __builtin_amdgcn_sched_barrier(0);                                          \
    asm volatile("s_waitcnt vmcnt(" #CNT ")" ::: "memory");                     \
    __builtin_amdgcn_s_barrier();                                               \
    RD(RDB);                                                                    \
    asm volatile("s_waitcnt lgkmcnt(0)" ::: "memory");                          \
    __builtin_amdgcn_sched_barrier(0);                                          \
    MF();                                                                       \
    __builtin_amdgcn_s_barrier();                                               \
} while (0)

#define GROUP3(T, MF) do {                                                      \
    TILE((T) + 0, MF, B0, B2, 1, 4);                                            \
    TILE((T) + 1, MF, B1, B0, 1, 4);                                            \
    TILE((T) + 2, MF, B2, B1, 1, 4);                                            \
} while (0)

    // prologue: stage tiles 0,1; stage(0) landed; BAR (cross-wave).
    STAGE(0, B0);
    STAGE(1, B1);
    __builtin_amdgcn_sched_barrier(0);
    asm volatile("s_waitcnt vmcnt(2)" ::: "memory");
    __builtin_amdgcn_s_barrier();

    // i8 segment: tiles 0..77 in 3-groups, then 78,79
    for (int t = 0; t < 78; t += 3) GROUP3(t, MFI);
    TILE(78, MFI, B0, B2, 1, 4);
    TILE(79, MFI, B1, B0, 1, 4);

    // dequantize: accF = accI * scaleC[col]/63.5
    #pragma unroll
    for (int mi = 0; mi < 4; ++mi)
        #pragma unroll
        for (int ni = 0; ni < 2; ++ni)
            #pragma unroll
            for (int rr = 0; rr < 4; ++rr)
                accF[mi][ni][rr] = (float)accI[mi][ni][rr] * sc_[ni];

    // bf16 segment: tile 80, groups 81..107, tail 108..111
    TILE(80, MFF, B2, B1, 1, 4);
    for (int t = 81; t < 108; t += 3) GROUP3(t, MFF);
    TILE(108, MFF, B0, B2, 1, 4);      // stages 110 -> B2
    TILE(109, MFF, B1, B0, 1, 4);      // stages 111 -> B0
    TILE(110, MFF, B2, B0, 0, 2);      // no stage; retire stage(110)
    TILE(111, MFF, B0, B0, 0, 0);      // retire stage(111)

#undef GROUP3
#undef TILE
#undef MFF
#undef MFI
#undef RD
#undef STAGE
#undef GLDS

    // epilogue: D row=(lane>>4)*4+reg, col=lane&15 ; + bias
    #pragma unroll
    for (int ni = 0; ni < 2; ++ni) {
        const int col = bn * 128 + wcbase + ni * 16 + fr;
        const float bv = bias_aug[col];
        #pragma unroll
        for (int mi = 0; mi < 4; ++mi) {
            #pragma unroll
            for (int rr = 0; rr < 4; ++rr) {
                const int row = bm * 128 + wrbase + mi * 16 + fg * 4 + rr;
                out[(size_t)row * OUT_F + col] = accF[mi][ni][rr] + bv;
            }
        }
    }
}

// ============================================================================
extern "C" void kernel_launch(void* const* d_in, const int* in_sizes, int n_in,
                              void* d_out, int out_size, void* d_ws, size_t ws_size,
                              hipStream_t stream) {
    const float* x    = (const float*)d_in[0];
    const float* W    = (const float*)d_in[1];
    const float* C    = (const float*)d_in[2];
    const float* bias = (const float*)d_in[3];
    float* out = (float*)d_out;

    char* ws = (char*)d_ws;
    char*  Arow     = ws;                               // 8192*7168 = 58,720,256
    char*  Brow     = ws + 58720256;                    // 1024*7168 =  7,340,032
    float* bias_aug = (float*)(ws + 66060288);          // 4 KB
    float* scaleC   = (float*)(ws + 66064384);          // 4 KB

    hipLaunchKernelGGL(prep_kernel, dim3(4096 + 1024), dim3(256), 0, stream,
                       x, W, C, bias, Arow, Brow, scaleC, bias_aug);
    hipLaunchKernelGGL(gemm_kernel, dim3(512), dim3(512), 0, stream,
                       Arow, Brow, scaleC, bias_aug, out);
}